// Round 1
// baseline (3406.566 us; speedup 1.0000x reference)
//
#include <hip/hip_runtime.h>
#include <hip/hip_bf16.h>
#include <math.h>

#define T_STEPS 100
#define B 256
#define Q 2048
#define H 1024
#define NIN (2 * Q) /* 4096 */

#define HP 1028 /* padded LDS row stride in floats: (s*1028+j)%32 varies with s -> <=2-way */

// h0[b][i] = b_start[i]  (zeros @ W_start.T == 0, W_start is dead); zero logits accumulator
__global__ void init_kernel(float* __restrict__ h, float* __restrict__ logits,
                            const float* __restrict__ b_start) {
    int idx = blockIdx.x * blockDim.x + threadIdx.x;
    if (idx < B * H) h[idx] = b_start[idx & (H - 1)];
    if (idx < T_STEPS * B) logits[idx] = 0.f;
}

// One recurrent step: h_next = tanh(h_cur @ Wm^T + bm + Wx[:,x_idx] + bx)
// Block = (student_group sg of 16 students) x (row_group rg of 64 rows).
// Also accumulates this step's logit partials: sum_i h_next[b,i] * Wy[y_idx[t,b], i].
__global__ __launch_bounds__(256) void step_kernel(
    const float* __restrict__ h_cur, float* __restrict__ h_next,
    float* __restrict__ logits,
    const float* __restrict__ Wm, const float* __restrict__ bm,
    const float* __restrict__ Wx, const float* __restrict__ bx_,
    const float* __restrict__ Wy,
    const int* __restrict__ x_idx, const int* __restrict__ y_idx,
    int t)
{
    __shared__ float h_lds[16 * HP];

    const int tid = threadIdx.x;
    const int rg  = blockIdx.x & 15;   // row group: rows [rg*64, rg*64+64)
    const int sg  = blockIdx.x >> 4;   // student group: students [sg*16, sg*16+16)
    const int s   = tid & 15;          // student within group
    const int rq  = tid >> 4;          // row quad 0..15
    const int b0  = sg * 16;
    const int b   = b0 + s;
    const int i0  = rg * 64 + rq * 4;  // first of this thread's 4 output rows

    // Stage h slice (16 students x 1024) into LDS, coalesced float4.
    for (int it = 0; it < 16; ++it) {
        int idx4 = it * 256 + tid;       // float4 index in [0, 4096)
        int ss   = idx4 >> 8;            // student 0..15
        int jj   = (idx4 & 255) << 2;    // float offset 0..1020
        float4 v = *reinterpret_cast<const float4*>(&h_cur[(b0 + ss) * H + jj]);
        *reinterpret_cast<float4*>(&h_lds[ss * HP + jj]) = v;
    }
    __syncthreads();

    float acc0 = 0.f, acc1 = 0.f, acc2 = 0.f, acc3 = 0.f;
    const float* wr0  = &Wm[(size_t)(i0 + 0) * H];
    const float* wr1  = &Wm[(size_t)(i0 + 1) * H];
    const float* wr2  = &Wm[(size_t)(i0 + 2) * H];
    const float* wr3  = &Wm[(size_t)(i0 + 3) * H];
    const float* hrow = &h_lds[s * HP];

    #pragma unroll 4
    for (int j = 0; j < H; j += 4) {
        float4 hv = *reinterpret_cast<const float4*>(&hrow[j]);
        float4 w0 = *reinterpret_cast<const float4*>(&wr0[j]);
        float4 w1 = *reinterpret_cast<const float4*>(&wr1[j]);
        float4 w2 = *reinterpret_cast<const float4*>(&wr2[j]);
        float4 w3 = *reinterpret_cast<const float4*>(&wr3[j]);
        acc0 += w0.x * hv.x + w0.y * hv.y + w0.z * hv.z + w0.w * hv.w;
        acc1 += w1.x * hv.x + w1.y * hv.y + w1.z * hv.z + w1.w * hv.w;
        acc2 += w2.x * hv.x + w2.y * hv.y + w2.z * hv.z + w2.w * hv.w;
        acc3 += w3.x * hv.x + w3.y * hv.y + w3.z * hv.z + w3.w * hv.w;
    }

    const int xc = x_idx[t * B + b];
    const int yc = y_idx[t * B + b];

    float4 bmv = *reinterpret_cast<const float4*>(&bm[i0]);
    float4 bxv = *reinterpret_cast<const float4*>(&bx_[i0]);
    float4 wyv = *reinterpret_cast<const float4*>(&Wy[(size_t)yc * H + i0]);

    float h0n = tanhf(acc0 + bmv.x + bxv.x + Wx[(size_t)(i0 + 0) * NIN + xc]);
    float h1n = tanhf(acc1 + bmv.y + bxv.y + Wx[(size_t)(i0 + 1) * NIN + xc]);
    float h2n = tanhf(acc2 + bmv.z + bxv.z + Wx[(size_t)(i0 + 2) * NIN + xc]);
    float h3n = tanhf(acc3 + bmv.w + bxv.w + Wx[(size_t)(i0 + 3) * NIN + xc]);

    *reinterpret_cast<float4*>(&h_next[b * H + i0]) = make_float4(h0n, h1n, h2n, h3n);

    // Logit partial over this thread's 4 rows, reduced over the 4 row-quads in a wave.
    float p = h0n * wyv.x + h1n * wyv.y + h2n * wyv.z + h3n * wyv.w;
    p += __shfl_down(p, 32);
    p += __shfl_down(p, 16);
    if ((tid & 48) == 0) // lane < 16 in its wave
        atomicAdd(&logits[t * B + b], p);
}

__global__ void final_kernel(const float* __restrict__ logits_ws,
                             const int* __restrict__ y_idx,
                             const float* __restrict__ truth,
                             const float* __restrict__ by,
                             float* __restrict__ out) {
    int idx = blockIdx.x * blockDim.x + threadIdx.x;
    if (idx >= T_STEPS * B) return;
    int yc = y_idx[idx];
    float l = logits_ws[idx] + by[yc];
    float pred = 1.f / (1.f + expf(-l));
    float tv = truth[idx];
    // log_sigmoid(x) = min(x,0) - log1p(exp(-|x|))
    float e = log1pf(expf(-fabsf(l)));
    float ls_pos = fminf(l, 0.f) - e;
    float ls_neg = fminf(-l, 0.f) - e;
    float loss = -(tv * ls_pos + (1.f - tv) * ls_neg);
    out[idx] = pred;
    out[T_STEPS * B + idx] = loss;
}

extern "C" void kernel_launch(void* const* d_in, const int* in_sizes, int n_in,
                              void* d_out, int out_size, void* d_ws, size_t ws_size,
                              hipStream_t stream) {
    const int*   x_idx   = (const int*)d_in[0];
    const int*   y_idx   = (const int*)d_in[1];
    const float* truth   = (const float*)d_in[2];
    const float* Wm      = (const float*)d_in[3];
    const float* bm      = (const float*)d_in[4];
    const float* Wx      = (const float*)d_in[5];
    const float* bx_     = (const float*)d_in[6];
    const float* Wy      = (const float*)d_in[7];
    const float* by      = (const float*)d_in[8];
    /* d_in[9] = W_start: dead (multiplied by zeros) */
    const float* b_start = (const float*)d_in[10];
    float* out = (float*)d_out;

    float* h_a    = (float*)d_ws;
    float* h_b    = h_a + (size_t)B * H;
    float* logits = h_b + (size_t)B * H;

    init_kernel<<<(B * H + 255) / 256, 256, 0, stream>>>(h_a, logits, b_start);

    float* hc = h_a;
    float* hn = h_b;
    for (int t = 0; t < T_STEPS; ++t) {
        step_kernel<<<256, 256, 0, stream>>>(hc, hn, logits, Wm, bm, Wx, bx_, Wy,
                                             x_idx, y_idx, t);
        float* tmp = hc; hc = hn; hn = tmp;
    }

    final_kernel<<<(T_STEPS * B + 255) / 256, 256, 0, stream>>>(logits, y_idx, truth, by, out);
}